// Round 5
// baseline (1125.402 us; speedup 1.0000x reference)
//
#include <hip/hip_runtime.h>
#include <cstdint>

// out = sigmoid(X @ W + b)
// X: (8192 x 4096) fp32 (detected), W: (4096 x 4096) fp32 K x N, b: (4096).
// Pipeline: prep (X->bf16, W->WT bf16 transposed) then bf16 MFMA GEMM.
// MODE 0 GEMM (round 5): 1-wave/SIMD deep-ILP pipeline. 256x256 block,
// BK=64, 4 waves (2x2), per-wave 128x128 output, 128KB dbuf LDS,
// ~430 regs/wave (acc 256 AGPR + B double-set 128 + A ping-pong 16).
// Rationale: R2-R4 (all 285us) showed 2-wave/SIMD lockstep serializes the
// LDS pipe (2800cyc) and matrix pipe (2480cyc) -> 5350cyc/K-tile. This
// design balances the pipes (128KB LDS traffic = 2050cyc vs 2060 matrix,
// -33% via square per-wave tile) and overlaps them via register lead-time:
// 8 windows/tile (16 MFMA each: 1 m-frag x 8 n x 2kk); A ping-pong with
// 1-window lead; next tile's B preloaded 4 reads/window over windows 4-7;
// staging = 16 gloads at ENTRY, certified by one vmcnt(0) at MID (4-window
// flight >= HBM latency); counted lgkmcnt{0,4} per window (FIFO enumerated,
// sched_barrier(0) pins A-before-B' issue so counts are exact).
// Barriers: ENTRY (buf^1 readers done -> staging safe) + MID (staging
// visible chip-wide -> next-tile preloads safe). Same XOR-swizzled LDS
// (0 conflicts), same MFMA shape/K-order (bit-identical numerics).
#define MDIM 8192
#define NDIM 4096
#define KDIM 4096
#define NT (KDIM / 64)  // 64 K-tiles of BK=64

typedef __bf16 bf16x8 __attribute__((ext_vector_type(8)));
typedef float f32x4 __attribute__((ext_vector_type(4)));

#define MFMA16 __builtin_amdgcn_mfma_f32_16x16x32_bf16
#define SB0 __builtin_amdgcn_sched_barrier(0)

__device__ __forceinline__ void gload_lds16(const void* g, void* l) {
    // async global->LDS, 16B/lane; LDS dest = wave-uniform base + lane*16
    __builtin_amdgcn_global_load_lds(
        (const __attribute__((address_space(1))) uint32_t*)g,
        (__attribute__((address_space(3))) uint32_t*)l, 16, 0, 0);
}

__device__ __forceinline__ unsigned short bf16_bits(float f) {
    __bf16 b = (__bf16)f;
    return __builtin_bit_cast(unsigned short, b);
}

// Called by ALL threads (uses __syncthreads_and). 1 if fp32, 0 if bf16.
__device__ __forceinline__ int detect_f32(const void* X) {
    int ok = 1;
    if (threadIdx.x < 128) {
        unsigned short h = ((const unsigned short*)X)[threadIdx.x];
        ok = (h <= 0x3F80);
    }
    return __syncthreads_and(ok) ? 0 : 1;
}

// ---------------- prep: X fp32->bf16 AND W (KxN) -> WT (NxK) bf16 ----------
__global__ __launch_bounds__(256) void prep(const void* __restrict__ X,
                                            const void* __restrict__ W,
                                            __bf16* __restrict__ Xb,
                                            __bf16* __restrict__ WT) {
    const int f32 = detect_f32(X);
    const int t = threadIdx.x;
    if (blockIdx.x < 8192) {
        if (!f32) return;  // bf16 mode: GEMM reads X directly
        const float* Xf = (const float*)X;
        const long xbase = (long)blockIdx.x * 4096;
#pragma unroll
        for (int rr = 0; rr < 4; ++rr) {
            const long idx = xbase + rr * 1024 + t * 4;
            float4 v = *(const float4*)(Xf + idx);
            unsigned short r[4] = {bf16_bits(v.x), bf16_bits(v.y),
                                   bf16_bits(v.z), bf16_bits(v.w)};
            *(uint2*)(Xb + idx) = *(const uint2*)r;
        }
        return;
    }
    __shared__ unsigned short tile[64 * 65];
    const int bid = blockIdx.x - 8192;
    const int n0 = (bid & 63) * 64;
    const int k0 = (bid >> 6) * 64;
    if (f32) {
        const float* Wf = (const float*)W;
#pragma unroll
        for (int p = 0; p < 4; ++p) {
            const int ch = p * 256 + t;
            const int kr = ch >> 4;
            const int nc = ch & 15;
            float4 v = *(const float4*)(Wf + (long)(k0 + kr) * NDIM + n0 + nc * 4);
            tile[(nc * 4 + 0) * 65 + kr] = bf16_bits(v.x);
            tile[(nc * 4 + 1) * 65 + kr] = bf16_bits(v.y);
            tile[(nc * 4 + 2) * 65 + kr] = bf16_bits(v.z);
            tile[(nc * 4 + 3) * 65 + kr] = bf16_bits(v.w);
        }
    } else {
        const __bf16* Wb = (const __bf16*)W;
#pragma unroll
        for (int p = 0; p < 2; ++p) {
            const int ch = p * 256 + t;
            const int kr = ch >> 3;
            const int nc = ch & 7;
            uint4 v = *(const uint4*)(Wb + (long)(k0 + kr) * NDIM + n0 + nc * 8);
            const unsigned short* e = (const unsigned short*)&v;
#pragma unroll
            for (int i = 0; i < 8; ++i) tile[(nc * 8 + i) * 65 + kr] = e[i];
        }
    }
    __syncthreads();
#pragma unroll
    for (int p = 0; p < 2; ++p) {
        const int ch = p * 256 + t;
        const int nr = ch >> 3;
        const int kc = ch & 7;
        unsigned short r[8];
#pragma unroll
        for (int i = 0; i < 8; ++i) r[i] = tile[nr * 65 + kc * 8 + i];
        *(uint4*)(WT + (long)(n0 + nr) * KDIM + k0 + kc * 8) = *(uint4*)r;
    }
}

// stand-alone transpose for MODE 1 (no Xb workspace)
__global__ __launch_bounds__(256) void transpose_w(const void* __restrict__ X,
                                                   const void* __restrict__ W,
                                                   __bf16* __restrict__ WT) {
    __shared__ unsigned short tile[64 * 65];
    const int f32 = detect_f32(X);
    const int t = threadIdx.x;
    const int k0 = blockIdx.y * 64;
    const int n0 = blockIdx.x * 64;
    if (f32) {
        const float* Wf = (const float*)W;
#pragma unroll
        for (int p = 0; p < 4; ++p) {
            const int ch = p * 256 + t;
            const int kr = ch >> 4;
            const int nc = ch & 15;
            float4 v = *(const float4*)(Wf + (long)(k0 + kr) * NDIM + n0 + nc * 4);
            tile[(nc * 4 + 0) * 65 + kr] = bf16_bits(v.x);
            tile[(nc * 4 + 1) * 65 + kr] = bf16_bits(v.y);
            tile[(nc * 4 + 2) * 65 + kr] = bf16_bits(v.z);
            tile[(nc * 4 + 3) * 65 + kr] = bf16_bits(v.w);
        }
    } else {
        const __bf16* Wb = (const __bf16*)W;
#pragma unroll
        for (int p = 0; p < 2; ++p) {
            const int ch = p * 256 + t;
            const int kr = ch >> 3;
            const int nc = ch & 7;
            uint4 v = *(const uint4*)(Wb + (long)(k0 + kr) * NDIM + n0 + nc * 8);
            const unsigned short* e = (const unsigned short*)&v;
#pragma unroll
            for (int i = 0; i < 8; ++i) tile[(nc * 8 + i) * 65 + kr] = e[i];
        }
    }
    __syncthreads();
#pragma unroll
    for (int p = 0; p < 2; ++p) {
        const int ch = p * 256 + t;
        const int nr = ch >> 3;
        const int kc = ch & 7;
        unsigned short r[8];
#pragma unroll
        for (int i = 0; i < 8; ++i) r[i] = tile[nr * 65 + kc * 8 + i];
        *(uint4*)(WT + (long)(n0 + nr) * KDIM + k0 + kc * 8) = *(uint4*)r;
    }
}

// ---------------- MODE 0 helpers ----------------
#define WAITL(N)                                                \
    do {                                                        \
        SB0;                                                    \
        asm volatile("s_waitcnt lgkmcnt(" #N ")" ::: "memory"); \
        SB0;                                                    \
    } while (0)

// window c: 16 MFMA = m-frag c x 8 n-frags x 2 kk (per-acc dep distance 8;
// per-acc order kk0 then kk1 -> bit-identical to prior rounds)
#define CLW(c)                                                              \
    do {                                                                    \
        _Pragma("unroll") for (int kk = 0; kk < 2; ++kk)                    \
            _Pragma("unroll") for (int j = 0; j < 8; ++j)                   \
                acc[c][j] = MFMA16(Aw[(c) & 1][kk], Bc[j][kk], acc[c][j],   \
                                   0, 0, 0);                                \
    } while (0)

#define ISS_A(p, base, fi)                                       \
    do {                                                         \
        Aw[p][0] = *(const bf16x8*)((base) + (fi)*1024 + soff0); \
        Aw[p][1] = *(const bf16x8*)((base) + (fi)*1024 + soff1); \
    } while (0)

#define ISS_B2(j0, base)                                                 \
    do {                                                                 \
        Bn[(j0)][0] = *(const bf16x8*)((base) + (j0)*1024 + soff0);      \
        Bn[(j0)][1] = *(const bf16x8*)((base) + (j0)*1024 + soff1);      \
        Bn[(j0) + 1][0] =                                                \
            *(const bf16x8*)((base) + ((j0) + 1) * 1024 + soff0);        \
        Bn[(j0) + 1][1] =                                                \
            *(const bf16x8*)((base) + ((j0) + 1) * 1024 + soff1);        \
    } while (0)

// One K-tile t (buffer DB). ko1 = K-offset of tile t+1 (staging target).
// Per-wave lgkm FIFO (issue->wait), steady state:
//   entry: [Bn45(4), A0'(2), Bn67(4)] from prev C5..C7  -> C0 waits 0
//   C0..C3 issue A_{c+1}(2) each                         -> waits 0
//   MID: vmcnt(0) drains the 16 ENTRY gloads (4-window flight); barrier
//   C4..C7 issue A(2) then B'batch(4) (SB0-pinned order) -> waits 0,4,4,4
template <int DB>
__device__ __forceinline__ void ktile(const __bf16* pa, const __bf16* pb,
                                      const __bf16* gA, const __bf16* gB,
                                      __bf16* lA, __bf16* lB, long ko1,
                                      int soff0, int soff1, f32x4 (&acc)[8][8],
                                      bf16x8 (&Bc)[8][2], bf16x8 (&Bn)[8][2],
                                      bf16x8 (&Aw)[2][2]) {
    const __bf16* paT = pa + DB * 16384;
    const __bf16* paN = pa + (DB ^ 1) * 16384;
    const __bf16* pbN = pb + (DB ^ 1) * 16384;
    const int so = (DB ^ 1) * 16384;
    // ---- ENTRY: all waves' reads of buf^1 (tile t-1) drained -> stage t+1
    SB0;
    __builtin_amdgcn_s_barrier();
    SB0;
#pragma unroll
    for (int i = 0; i < 8; ++i)
        gload_lds16(gA + (long)(i * 32) * KDIM + ko1, lA + so + i * 2048);
#pragma unroll
    for (int i = 0; i < 8; ++i)
        gload_lds16(gB + (long)(i * 32) * KDIM + ko1, lB + so + i * 2048);
    SB0;
    // ---- windows 0..3 ----
    WAITL(0);
    CLW(0);
    SB0;
    ISS_A(1, paT, 1);
    SB0;
    WAITL(0);
    CLW(1);
    SB0;
    ISS_A(0, paT, 2);
    SB0;
    WAITL(0);
    CLW(2);
    SB0;
    ISS_A(1, paT, 3);
    SB0;
    WAITL(0);
    CLW(3);
    SB0;
    ISS_A(0, paT, 4);
    SB0;
    // ---- MID: staging of t+1 visible chip-wide -> t+1 preloads safe ----
    asm volatile("s_waitcnt vmcnt(0)" ::: "memory");
    SB0;
    __builtin_amdgcn_s_barrier();
    SB0;
    // ---- windows 4..7 (A then B' per window, order pinned by SB0) ----
    WAITL(0);
    CLW(4);
    SB0;
    ISS_A(1, paT, 5);
    SB0;
    ISS_B2(0, pbN);
    SB0;
    WAITL(4);
    CLW(5);
    SB0;
    ISS_A(0, paT, 6);
    SB0;
    ISS_B2(2, pbN);
    SB0;
    WAITL(4);
    CLW(6);
    SB0;
    ISS_A(1, paT, 7);
    SB0;
    ISS_B2(4, pbN);
    SB0;
    WAITL(4);
    CLW(7);
    SB0;
    ISS_A(0, paN, 0);  // A-frag0 of tile t+1
    SB0;
    ISS_B2(6, pbN);
    SB0;
}

__global__ __launch_bounds__(256, 1) void gemm256(
    const void* __restrict__ X, const __bf16* __restrict__ Xb,
    const __bf16* __restrict__ WT, const void* __restrict__ bias,
    void* __restrict__ out) {
    __shared__ __bf16 sA[2][256][64];  // 64 KB (double-buffered A tile)
    __shared__ __bf16 sB[2][256][64];  // 64 KB
    const int f32 = detect_f32(X);
    const __bf16* __restrict__ Abf = f32 ? Xb : (const __bf16*)X;
    const int t = threadIdx.x;
    const int lane = t & 63;
    const int wid = t >> 6;   // 0..3
    const int wm = wid >> 1;  // 0..1  (wave's 128-row half)
    const int wn = wid & 1;   // 0..1  (wave's 128-col half)
    const int lrow = lane & 15;
    const int quad = lane >> 4;
    const int l7 = lrow & 7;

    // bijective XCD swizzle (512 wgs % 8 == 0): 64 consecutive tiles per XCD
    const int flat = blockIdx.x;
    const int swz = (flat & 7) * (512 / 8) + (flat >> 3);
    const long m0 = (long)(swz >> 4) * 256;  // 32 row tiles
    const long n0 = (long)(swz & 15) * 256;  // 16 col tiles

    // staging: lane = r8*8+c8 fetches global chunk (c8^r8) of row r8; LDS
    // stays glds-linear so slot s of row r holds chunk s^(r&7) (proven swizzle)
    const int r8 = lane >> 3;
    const int c8 = lane & 7;
    const int cs = (c8 ^ r8) * 8;
    // each wave stages 8 A-slabs + 8 B-slabs (slab i = rows wid*8+i*32..+7)
    const __bf16* gA = Abf + (m0 + wid * 8 + r8) * KDIM + cs;
    const __bf16* gB = WT + (n0 + wid * 8 + r8) * KDIM + cs;
    __bf16* lA = &sA[0][wid * 8][0];  // wave-uniform LDS bases
    __bf16* lB = &sB[0][wid * 8][0];

    // per-lane swizzled fragment offsets (k-chunk ks*4+quad, slot ^= lrow&7)
    const int soff0 = (quad ^ l7) * 8;
    const int soff1 = ((4 + quad) ^ l7) * 8;
    const __bf16* pa = &sA[0][wm * 128 + lrow][0];
    const __bf16* pb = &sB[0][wn * 128 + lrow][0];

    f32x4 acc[8][8] = {};
    bf16x8 Ba[8][2], Bb[8][2], Aw[2][2];

    // prologue: stage tile0 -> buf0 (16 gloads), drain, barrier, preload
    // B(t0) all 8 frag-pairs + A-frag0(t0).
#pragma unroll
    for (int i = 0; i < 8; ++i)
        gload_lds16(gA + (long)(i * 32) * KDIM, lA + i * 2048);
#pragma unroll
    for (int i = 0; i < 8; ++i)
        gload_lds16(gB + (long)(i * 32) * KDIM, lB + i * 2048);
    SB0;
    asm volatile("s_waitcnt vmcnt(0)" ::: "memory");
    SB0;
    __builtin_amdgcn_s_barrier();
    SB0;
#pragma unroll
    for (int j = 0; j < 8; ++j) {
        Ba[j][0] = *(const bf16x8*)(pb + j * 1024 + soff0);
        Ba[j][1] = *(const bf16x8*)(pb + j * 1024 + soff1);
    }
    Aw[0][0] = *(const bf16x8*)(pa + soff0);
    Aw[0][1] = *(const bf16x8*)(pa + soff1);
    SB0;

#pragma unroll 1
    for (int tt = 0; tt < NT; tt += 2) {
        ktile<0>(pa, pb, gA, gB, lA, lB, (long)((tt + 1) & (NT - 1)) * 64,
                 soff0, soff1, acc, Ba, Bb, Aw);
        ktile<1>(pa, pb, gA, gB, lA, lB, (long)((tt + 2) & (NT - 1)) * 64,
                 soff0, soff1, acc, Bb, Ba, Aw);
    }

    // epilogue: C/D layout col=lane&15, row=quad*4+reg
    if (f32) {
        float* of = (float*)out;
        const float* bf = (const float*)bias;
#pragma unroll
        for (int j = 0; j < 8; ++j) {
            const int col = (int)n0 + wn * 128 + j * 16 + lrow;
            const float bv = bf[col];
#pragma unroll
            for (int i = 0; i < 8; ++i) {
                const int rr = (int)m0 + wm * 128 + i * 16 + quad * 4;
                const long rbase = (long)rr * NDIM + col;
#pragma unroll
                for (int r = 0; r < 4; ++r) {
                    const float x = acc[i][j][r] + bv;
                    of[rbase + (long)r * NDIM] = 1.0f / (1.0f + __expf(-x));
                }
            }
        }
    } else {
        __bf16* ob = (__bf16*)out;
        const __bf16* bb = (const __bf16*)bias;
#pragma unroll
        for (int j = 0; j < 8; ++j) {
            const int col = (int)n0 + wn * 128 + j * 16 + lrow;
            const float bv = (float)bb[col];
#pragma unroll
            for (int i = 0; i < 8; ++i) {
                const int rr = (int)m0 + wm * 128 + i * 16 + quad * 4;
                const long rbase = (long)rr * NDIM + col;
#pragma unroll
                for (int r = 0; r < 4; ++r) {
                    const float x = acc[i][j][r] + bv;
                    ob[rbase + (long)r * NDIM] = (__bf16)(1.0f / (1.0f + __expf(-x)));
                }
            }
        }
    }
}

// ---------------- verified BK=32 fallbacks (MODE 1/2), unchanged ----------
template <int MODE>
__global__ __launch_bounds__(256) void gemm_bias_sigmoid(
    const void* __restrict__ X, const __bf16* __restrict__ Xb,
    const void* __restrict__ Wp, const __bf16* __restrict__ WT,
    const void* __restrict__ bias, void* __restrict__ out) {
    __shared__ __bf16 sA[128 * 64];
    __shared__ __bf16 sB[128 * 64];
    const int f32 = detect_f32(X);
    const int t = threadIdx.x;
    const int lane = t & 63;
    const int wid = t >> 6;
    const int m0 = blockIdx.y * 128;
    const int n0 = blockIdx.x * 128;
    const int wm = (wid & 1) * 64;
    const int wn = (wid >> 1) * 64;
    const int lrow = lane & 15;
    const int quad = lane >> 4;

    f32x4 acc[4][4] = {};

    {
        const int srow = t >> 2;
        const int schk = t & 3;
        __bf16* ldsA = sA + wid * 512;
        __bf16* ldsB = sB + wid * 512;
        const int arow = t >> 1;
        const int acol = (t & 1) * 16;
        const int fp = t & 15;
        const int fc = t >> 4;
        uint32_t* sB32 = (uint32_t*)sB;

        auto compute = [&]() {
            bf16x8 aF[4], bFr[4];
            const __bf16* pa = sA + (wm + lrow) * 32 + quad * 8;
            const __bf16* pb = sB + (wn + lrow) * 32 + quad * 8;
#pragma unroll
            for (int i = 0; i < 4; ++i) aF[i] = *(const bf16x8*)(pa + i * 512);
#pragma unroll
            for (int j = 0; j < 4; ++j) bFr[j] = *(const bf16x8*)(pb + j * 512);
#pragma unroll
            for (int i = 0; i < 4; ++i)
#pragma unroll
                for (int j = 0; j < 4; ++j)
                    acc[i][j] = MFMA16(aF[i], bFr[j], acc[i][j], 0, 0, 0);
        };

        if (MODE == 1 && !f32) {
            const __bf16* gA = (const __bf16*)X + (long)(m0 + srow) * KDIM + schk * 8;
            const __bf16* gB = WT + (long)(n0 + srow) * KDIM + schk * 8;
            for (int kt = 0; kt < KDIM / 32; ++kt) {
                const __bf16* a0 = gA + kt * 32;
                gload_lds16(a0, ldsA);
                gload_lds16(a0 + (long)64 * KDIM, ldsA + 2048);
                const __bf16* b0 = gB + kt * 32;
                gload_lds16(b0, ldsB);
                gload_lds16(b0 + (long)64 * KDIM, ldsB + 2048);
                __syncthreads();
                compute();
                __syncthreads();
            }
        } else if (MODE == 1) {
            const float* Xf = (const float*)X;
            const __bf16* gB = WT + (long)(n0 + srow) * KDIM + schk * 8;
            for (int kt = 0; kt < KDIM / 32; ++kt) {
                const __bf16* b0 = gB + kt * 32;
                gload_lds16(b0, ldsB);
                gload_lds16(b0 + (long)64 * KDIM, ldsB + 2048);
                const float* ap = Xf + (long)(m0 + arow) * KDIM + kt * 32 + acol;
                float4 v0 = *(const float4*)(ap);
                float4 v1 = *(const float4*)(ap + 4);
                float4 v2 = *(const float4*)(ap + 8);
                float4 v3 = *(const float4*)(ap + 12);
                unsigned short r[16] = {
                    bf16_bits(v0.x), bf16_bits(v0.y), bf16_bits(v0.z), bf16_bits(v0.w),
                    bf16_bits(v1.x), bf16_bits(v1.y), bf16_bits(v1.z), bf16_bits(v1.w),
                    bf16_bits(v2.x), bf16_bits(v2.y), bf16_bits(v2.z), bf16_bits(v2.w),
                    bf16_bits(v3.x), bf16_bits(v3.y), bf16_bits(v3.z), bf16_bits(v3.w)};
                *(uint4*)(sA + arow * 32 + acol) = *(const uint4*)(r);
                *(uint4*)(sA + arow * 32 + acol + 8) = *(const uint4*)(r + 8);
                __syncthreads();
                compute();
                __syncthreads();
            }
        } else if (MODE == 2 && !f32) {
            const __bf16* gA = (const __bf16*)X + (long)(m0 + srow) * KDIM + schk * 8;
            const __bf16* Wb = (const __bf16*)Wp;
            for (int kt = 0; kt < KDIM / 32; ++kt) {
                const __bf16* a0 = gA + kt * 32;
                gload_lds16(a0, ldsA);
                gload_lds16(a0 + (long)64 * KDIM, ldsA + 2048);
                const __bf16* w0 = Wb + (long)(kt * 32 + 2 * fp) * NDIM + n0 + fc * 8;
                uint4 g0 = *(const uint4*)(w0);
                uint4 g1 = *(const uint4*)(w0 + NDIM);
                const unsigned short* e0 = (const unsigned short*)&g0;
                const unsigned short* e1 = (const unsigned short*)&g1;
#pragma unroll
                for (int i = 0; i < 8; ++i)
                    sB32[(fc * 8 + i) * 16 + fp] =
                        (uint32_t)e0[i] | ((uint32_t)e1[i] << 16);
                __syncthreads();
                compute();
                __syncthreads();
            }
        } else if (MODE == 2) {
            const float* Xf = (const float*)X;
            const float* Wf = (const float*)Wp;
            for (int kt = 0; kt < KDIM / 32; ++kt) {
                const float* ap = Xf + (long)(m0 + arow) * KDIM + kt * 32 + acol;
                float4 v0 = *(const float4*)(ap);
                float4 v1 = *(const float4*)(ap + 4);
                float4 v2 = *(const float4*)(ap + 8);
                float4 v3 = *(const float4*)(ap + 12);
                unsigned short r[16] = {
                    bf16_bits(v0.x), bf16_bits(v0.y), bf16_bits(v0.z), bf16_bits(v0.w),
                    bf16_bits(v1.x), bf16_bits(v1.y), bf16_bits(v1.z), bf16_bits(v1.w),
                    bf16_bits(v2.x), bf16_bits(v2.y), bf16_bits(v2.z), bf16_bits(v2.w),
                    bf16_bits(v3.x), bf16_bits(v3.y), bf16_bits(v3.z), bf16_bits(v3.w)};
                *(uint4*)(sA + arow * 32 + acol) = *(const uint4*)(r);
                *(uint4*)(sA + arow * 32 + acol + 8) = *(const uint4*)(r + 8);
                const float* w0 = Wf + (long)(kt * 32 + 2 * fp) * NDIM + n0 + fc * 8;
                float4 u0 = *(const float4*)(w0);
                float4 u1 = *(const float4*)(w0 + 4);
                float4 u2 = *(const float4*)(w0 + NDIM);
                float4 u3 = *(const float4*)(w0 + NDIM + 4);
                float k0v[8] = {u0.x, u0.y, u0.z, u0.w, u1.x, u1.y, u1.z, u1.w};
                float k1v[8] = {u2.x, u2.y, u2.z, u2.w, u3.x, u3.y, u3.z, u3.w};
#pragma unroll
                for (int i = 0; i < 8; ++i)
                    sB32[(fc * 8 + i) * 16 + fp] =
                        (uint32_t)bf16_bits(k0v[i]) |
                        ((uint32_t)bf16_bits(k1v[i]) << 16);
                __syncthreads();
                compute();
                __syncthreads();
            }
        }
    }

    // epilogue: C/D layout col=lane&15, row=quad*4+reg
    const int crow = m0 + wm + quad * 4;
    if (f32) {
        float* of = (float*)out;
        const float* bf = (const float*)bias;
#pragma unroll
        for (int j = 0; j < 4; ++j) {
            const int col = n0 + wn + j * 16 + lrow;
            const float bv = bf[col];
#pragma unroll
            for (int i = 0; i < 4; ++i) {
                const long rbase = (long)(crow + i * 16) * NDIM + col;
#pragma unroll
                for (int r = 0; r < 4; ++r) {
                    const float x = acc[i][j][r] + bv;
                    of[rbase + (long)r * NDIM] = 1.0f / (1.0f + __expf(-x));
                }
            }
        }
    } else {
        __bf16* ob = (__bf16*)out;
        const __bf16* bb = (const __bf16*)bias;
#pragma unroll
        for (int j = 0; j < 4; ++j) {
            const int col = n0 + wn + j * 16 + lrow;
            const float bv = (float)bb[col];
#pragma unroll
            for (int i = 0; i < 4; ++i) {
                const long rbase = (long)(crow + i * 16) * NDIM + col;
#pragma unroll
                for (int r = 0; r < 4; ++r) {
                    const float x = acc[i][j][r] + bv;
                    ob[rbase + (long)r * NDIM] = (__bf16)(1.0f / (1.0f + __expf(-x)));
                }
            }
        }
    }
}

extern "C" void kernel_launch(void* const* d_in, const int* in_sizes, int n_in,
                              void* d_out, int out_size, void* d_ws,
                              size_t ws_size, hipStream_t stream) {
    const void* X = d_in[0];     // input_data (8192 x 4096)
    const void* W = d_in[1];     // W (4096 x 4096), K x N
    const void* bias = d_in[2];  // hidden_bias (4096)

    const size_t wt_bytes = (size_t)KDIM * NDIM * sizeof(__bf16);  // 33.5 MB
    const size_t xb_bytes = (size_t)MDIM * KDIM * sizeof(__bf16);  // 67 MB

    if (ws_size >= wt_bytes + xb_bytes) {
        __bf16* WT = (__bf16*)d_ws;
        __bf16* Xb = (__bf16*)((char*)d_ws + wt_bytes);
        prep<<<8192 + 4096, 256, 0, stream>>>(X, W, Xb, WT);
        gemm256<<<dim3((MDIM / 256) * (NDIM / 256)), 256, 0, stream>>>(
            X, Xb, WT, bias, d_out);
    } else if (ws_size >= wt_bytes) {
        __bf16* WT = (__bf16*)d_ws;
        transpose_w<<<dim3(NDIM / 64, KDIM / 64), 256, 0, stream>>>(X, W, WT);
        dim3 gg(NDIM / 128, MDIM / 128);
        gemm_bias_sigmoid<1><<<gg, 256, 0, stream>>>(X, nullptr, W, WT, bias, d_out);
    } else {
        dim3 gg(NDIM / 128, MDIM / 128);
        gemm_bias_sigmoid<2><<<gg, 256, 0, stream>>>(X, nullptr, W, nullptr, bias, d_out);
    }
}